// Round 7
// baseline (700.644 us; speedup 1.0000x reference)
//
#include <hip/hip_runtime.h>
#include <math.h>

#define TPB 256
typedef unsigned short ushort_t;
typedef unsigned int uint_t;
typedef __attribute__((ext_vector_type(8))) short bf16x8;
typedef __attribute__((ext_vector_type(4))) float f32x4;

__device__ __forceinline__ float bf2f(ushort_t h) {
    return __uint_as_float(((uint_t)h) << 16);
}
__device__ __forceinline__ ushort_t f2bf(float f) {
    uint_t u = __float_as_uint(f);
    u += 0x7fff + ((u >> 16) & 1);
    return (ushort_t)(u >> 16);
}
__device__ __forceinline__ uint_t pack2(float x, float y) {
    return (uint_t)f2bf(x) | ((uint_t)f2bf(y) << 16);
}

// ==================== CSR build + GCN norm ====================
__global__ void rank_kernel(const int* __restrict__ col, int* __restrict__ cnt,
                            int* __restrict__ pos, int E) {
    int e = blockIdx.x * blockDim.x + threadIdx.x;
    if (e < E) pos[e] = atomicAdd(&cnt[col[e]], 1);
}

__global__ void scan_block(const int* __restrict__ cnt, int* __restrict__ incl,
                           int* __restrict__ bsum, int N) {
    __shared__ int s[TPB];
    int i = blockIdx.x * TPB + threadIdx.x;
    s[threadIdx.x] = (i < N) ? cnt[i] : 0;
    __syncthreads();
    for (int d = 1; d < TPB; d <<= 1) {
        int t = (threadIdx.x >= d) ? s[threadIdx.x - d] : 0;
        __syncthreads();
        s[threadIdx.x] += t;
        __syncthreads();
    }
    if (i < N) incl[i] = s[threadIdx.x];
    if (threadIdx.x == TPB - 1) bsum[blockIdx.x] = s[TPB - 1];
}

__global__ void scan_bsums(int* __restrict__ bsum, int nb) {
    __shared__ int s[512];
    int t = threadIdx.x;
    int v = (t < nb) ? bsum[t] : 0;
    s[t] = v;
    __syncthreads();
    for (int d = 1; d < 512; d <<= 1) {
        int u = (t >= d) ? s[t - d] : 0;
        __syncthreads();
        s[t] += u;
        __syncthreads();
    }
    if (t < nb) bsum[t] = s[t] - v;
}

// rowstart + dinv fused
__global__ void finalize_csr(const int* __restrict__ incl, const int* __restrict__ bsum,
                             const int* __restrict__ cnt, int* __restrict__ rowstart,
                             float* __restrict__ dinv, int N) {
    int i = blockIdx.x * TPB + threadIdx.x;
    if (i < N) {
        rowstart[i + 1] = incl[i] + bsum[blockIdx.x];
        int d = cnt[i];
        dinv[i] = (d > 0) ? rsqrtf((float)d) : 0.0f;
    }
    if (i == 0) rowstart[0] = 0;
}

__global__ void fill_csr(const int* __restrict__ row, const int* __restrict__ col,
                         const int* __restrict__ rowstart, const int* __restrict__ pos,
                         int* __restrict__ srcidx, int E) {
    int e = blockIdx.x * blockDim.x + threadIdx.x;
    if (e < E) srcidx[rowstart[col[e]] + pos[e]] = row[e];
}

// ==================== conversion ====================
__global__ void cvt4_kernel(const float4* __restrict__ src, uint2* __restrict__ dst, int n4) {
    int i = blockIdx.x * blockDim.x + threadIdx.x;
    if (i < n4) {
        float4 v = src[i];
        dst[i] = make_uint2(pack2(v.x, v.y), pack2(v.z, v.w));
    }
}

// ==================== weight pre-swizzle (bf16 B-fragment order) ====================
#define SWZ_A 32768
#define SWZ_B 24576
#define SWZ_C 12288
#define SWZ_D 12288
__global__ void swz_all(const float* __restrict__ w1_init, const float* __restrict__ w1,
                        const float* __restrict__ w1_root, const float* __restrict__ w2_init,
                        const float* __restrict__ w2, const float* __restrict__ w2_root,
                        short* __restrict__ dst) {
    int idx = blockIdx.x * blockDim.x + threadIdx.x;
    int region, base, CH, CT;
    if (idx < SWZ_A)                          { region = 0; base = 0; CH = 4; CT = 8; }
    else if (idx < SWZ_A + SWZ_B)             { region = 1; base = SWZ_A; CH = 6; CT = 4; }
    else if (idx < SWZ_A + SWZ_B + SWZ_C)     { region = 2; base = SWZ_A + SWZ_B; CH = 2; CT = 6; }
    else if (idx < SWZ_A + SWZ_B + SWZ_C + SWZ_D)
                                              { region = 3; base = SWZ_A + SWZ_B + SWZ_C; CH = 4; CT = 3; }
    else return;
    int r = idx - base;
    int j = r & 7, ln = (r >> 3) & 63;
    int rest = r >> 9;
    int ct = rest % CT, c = (rest / CT) % CH, k = rest / (CT * CH);
    int col = ct * 16 + (ln & 15);
    int kl = (ln >> 4) * 8 + j;
    float v = 0.0f;
    if (region == 0) {              // L1-t0: x(128) -> [init(64) | root_t0(64)]
        int kk = c * 32 + kl;
        if (col < 64)       v = w1_init[((size_t)k * 128 + kk) * 64 + col];
        else                v = w1_root[((size_t)k * 128 + kk) * 64 + (col - 64)];
    } else if (region == 1) {       // L1-t1: c<2: agg(64)@w1 ; c>=2: x(128)@root_t1
        if (c < 2) { int kk = c * 32 + kl;        v = w1[((size_t)k * 64 + kk) * 64 + col]; }
        else       { int kk = (c - 2) * 32 + kl;  v = w1_root[((size_t)(2 + k) * 128 + kk) * 64 + col]; }
    } else if (region == 2) {       // L2-t0: h(64) -> [init(41,pad48) | root_t0(41,pad48)]
        int kk = c * 32 + kl;
        if (col < 48) { if (col < 41)            v = w2_init[((size_t)k * 64 + kk) * 41 + col]; }
        else          { int c2 = col - 48; if (c2 < 41) v = w2_root[((size_t)k * 64 + kk) * 41 + c2]; }
    } else {                        // L2-t1: c<2: agg(48,rows41)@w2 ; c>=2: h(64)@root_t1
        if (c < 2) { int kk = c * 32 + kl;       if (kk < 41 && col < 41) v = w2[((size_t)k * 41 + kk) * 41 + col]; }
        else       { int kk = (c - 2) * 32 + kl; if (col < 41)            v = w2_root[((size_t)(2 + k) * 64 + kk) * 41 + col]; }
    }
    dst[(size_t)base + r] = (short)f2bf(v);
}

// ==================== t0 GEMM (per-k): s2 @ [Wa | Wb] -> outH bf16 + pre bf16 ====================
// ct < CTA -> outH payload [n][2][CTA*8] uints; ct >= CTA -> pre payload [n][2][(CT-CTA)*8] uints (+biasB)
template<int CT, int CTA, int CH>
__global__ __launch_bounds__(256)
void gemm_t0(const ushort_t* __restrict__ s2, int s2s, const short* __restrict__ fragbuf,
             const float* __restrict__ biasB, int FB, int N,
             uint_t* __restrict__ pre, uint_t* __restrict__ outH) {
    constexpr int PP = (CT - CTA) * 8;
    constexpr int PA = CTA * 8;
    const int k = blockIdx.y;
    const int n0 = blockIdx.x * 128;
    const int t = threadIdx.x;
    const int w = t >> 6, lane = t & 63, quad = lane >> 4, lr = lane & 15;
    const short* fb = fragbuf + (size_t)k * CH * CT * 512;

    int r0 = n0 + w * 32 + lr;
    int m0 = r0 < N ? r0 : N - 1;
    int m1 = (r0 + 16) < N ? (r0 + 16) : N - 1;

    f32x4 acc[2][CT];
#pragma unroll
    for (int rt = 0; rt < 2; ++rt)
#pragma unroll
        for (int ct = 0; ct < CT; ++ct) acc[rt][ct] = (f32x4){0.f, 0.f, 0.f, 0.f};

#pragma unroll
    for (int c = 0; c < CH; ++c) {
        int off = c * 32 + quad * 8;
        bf16x8 a0 = *(const bf16x8*)&s2[(size_t)m0 * s2s + off];
        bf16x8 a1 = *(const bf16x8*)&s2[(size_t)m1 * s2s + off];
#pragma unroll
        for (int ct = 0; ct < CT; ++ct) {
            bf16x8 b = *(const bf16x8*)&fb[((size_t)c * CT + ct) * 512 + lane * 8];
            acc[0][ct] = __builtin_amdgcn_mfma_f32_16x16x32_bf16(a0, b, acc[0][ct], 0, 0, 0);
            acc[1][ct] = __builtin_amdgcn_mfma_f32_16x16x32_bf16(a1, b, acc[1][ct], 0, 0, 0);
        }
    }

#pragma unroll
    for (int rt = 0; rt < 2; ++rt) {
#pragma unroll
        for (int i = 0; i < 4; ++i) {
            int n = n0 + w * 32 + rt * 16 + quad * 4 + i;
            if (n >= N) continue;     // uniform across lr-pairs (n independent of lr)
#pragma unroll
            for (int ct = 0; ct < CT; ++ct) {
                int col = ct * 16 + lr;
                float v = acc[rt][ct][i];
                if (ct < CTA) {
                    float vn = __shfl_xor(v, 1);
                    if (!(lr & 1))
                        outH[((size_t)n * 2 + k) * PA + (col >> 1)] = pack2(v, vn);
                } else {
                    int c2 = col - CTA * 16;
                    if (c2 < FB) v += biasB[(size_t)k * FB + c2];
                    float vn = __shfl_xor(v, 1);
                    if (!(lr & 1))
                        pre[((size_t)n * 2 + k) * PP + (c2 >> 1)] = pack2(v, vn);
                }
            }
        }
    }
}

// ==================== t1 GEMM layer1: relu+mean -> hh bf16 ====================
__global__ __launch_bounds__(256)
void gemm_t1_l1(const ushort_t* __restrict__ s1, const ushort_t* __restrict__ xh,
                const short* __restrict__ fragbuf, const float* __restrict__ bias,
                int N, uint_t* __restrict__ hhU) {
    constexpr int CT = 4, CH = 6;
    const int n0 = blockIdx.x * 128;
    const int t = threadIdx.x;
    const int w = t >> 6, lane = t & 63, quad = lane >> 4, lr = lane & 15;

    int r0 = n0 + w * 32 + lr;
    int m0 = r0 < N ? r0 : N - 1;
    int m1 = (r0 + 16) < N ? (r0 + 16) : N - 1;

    f32x4 acc[2][2][CT];
#pragma unroll
    for (int k = 0; k < 2; ++k)
#pragma unroll
        for (int rt = 0; rt < 2; ++rt)
#pragma unroll
            for (int ct = 0; ct < CT; ++ct) acc[k][rt][ct] = (f32x4){0.f, 0.f, 0.f, 0.f};

#pragma unroll
    for (int c = 0; c < CH; ++c) {
        bf16x8 a0[2], a1[2];
        if (c < 2) {
            int off = c * 32 + quad * 8;
#pragma unroll
            for (int k = 0; k < 2; ++k) {
                a0[k] = *(const bf16x8*)&s1[((size_t)m0 * 2 + k) * 64 + off];
                a1[k] = *(const bf16x8*)&s1[((size_t)m1 * 2 + k) * 64 + off];
            }
        } else {
            int off = (c - 2) * 32 + quad * 8;
            a0[0] = a0[1] = *(const bf16x8*)&xh[(size_t)m0 * 128 + off];
            a1[0] = a1[1] = *(const bf16x8*)&xh[(size_t)m1 * 128 + off];
        }
#pragma unroll
        for (int k = 0; k < 2; ++k) {
            const short* fb = fragbuf + (size_t)k * CH * CT * 512;
#pragma unroll
            for (int ct = 0; ct < CT; ++ct) {
                bf16x8 b = *(const bf16x8*)&fb[((size_t)c * CT + ct) * 512 + lane * 8];
                acc[k][0][ct] = __builtin_amdgcn_mfma_f32_16x16x32_bf16(a0[k], b, acc[k][0][ct], 0, 0, 0);
                acc[k][1][ct] = __builtin_amdgcn_mfma_f32_16x16x32_bf16(a1[k], b, acc[k][1][ct], 0, 0, 0);
            }
        }
    }

#pragma unroll
    for (int rt = 0; rt < 2; ++rt) {
#pragma unroll
        for (int i = 0; i < 4; ++i) {
            int n = n0 + w * 32 + rt * 16 + quad * 4 + i;
            if (n >= N) continue;
#pragma unroll
            for (int ct = 0; ct < CT; ++ct) {
                int col = ct * 16 + lr;
                float v0 = fmaxf(acc[0][rt][ct][i] + bias[col], 0.0f);
                float v1 = fmaxf(acc[1][rt][ct][i] + bias[64 + col], 0.0f);
                float m = 0.5f * (v0 + v1);
                float mn = __shfl_xor(m, 1);
                if (!(lr & 1)) hhU[(size_t)n * 32 + (col >> 1)] = pack2(m, mn);
            }
        }
    }
}

// ===== t1 GEMM layer2: relu+mean+log_softmax -> d_out f32 =====
__global__ __launch_bounds__(256)
void gemm_t1_l2(const ushort_t* __restrict__ s1, const ushort_t* __restrict__ hh,
                const short* __restrict__ fragbuf, const float* __restrict__ bias,
                int N, float* __restrict__ out) {
    constexpr int CT = 3, CH = 4;
    const int n0 = blockIdx.x * 128;
    const int t = threadIdx.x;
    const int w = t >> 6, lane = t & 63, quad = lane >> 4, lr = lane & 15;

    int r0 = n0 + w * 32 + lr;
    int m0 = r0 < N ? r0 : N - 1;
    int m1 = (r0 + 16) < N ? (r0 + 16) : N - 1;

    f32x4 acc[2][2][CT];
#pragma unroll
    for (int k = 0; k < 2; ++k)
#pragma unroll
        for (int rt = 0; rt < 2; ++rt)
#pragma unroll
            for (int ct = 0; ct < CT; ++ct) acc[k][rt][ct] = (f32x4){0.f, 0.f, 0.f, 0.f};

#pragma unroll
    for (int c = 0; c < CH; ++c) {
        bf16x8 a0[2], a1[2];
        if (c < 2) {
            int off = c * 32 + quad * 8;
#pragma unroll
            for (int k = 0; k < 2; ++k) {
                a0[k] = *(const bf16x8*)&s1[((size_t)m0 * 2 + k) * 48 + off];
                a1[k] = *(const bf16x8*)&s1[((size_t)m1 * 2 + k) * 48 + off];
            }
        } else {
            int off = (c - 2) * 32 + quad * 8;
            a0[0] = a0[1] = *(const bf16x8*)&hh[(size_t)m0 * 64 + off];
            a1[0] = a1[1] = *(const bf16x8*)&hh[(size_t)m1 * 64 + off];
        }
#pragma unroll
        for (int k = 0; k < 2; ++k) {
            const short* fb = fragbuf + (size_t)k * CH * CT * 512;
#pragma unroll
            for (int ct = 0; ct < CT; ++ct) {
                bf16x8 b = *(const bf16x8*)&fb[((size_t)c * CT + ct) * 512 + lane * 8];
                acc[k][0][ct] = __builtin_amdgcn_mfma_f32_16x16x32_bf16(a0[k], b, acc[k][0][ct], 0, 0, 0);
                acc[k][1][ct] = __builtin_amdgcn_mfma_f32_16x16x32_bf16(a1[k], b, acc[k][1][ct], 0, 0, 0);
            }
        }
    }

#pragma unroll
    for (int rt = 0; rt < 2; ++rt) {
#pragma unroll
        for (int i = 0; i < 4; ++i) {
            int n = n0 + w * 32 + rt * 16 + quad * 4 + i;
            float m[CT];
            float mx = -1e30f;
#pragma unroll
            for (int ct = 0; ct < CT; ++ct) {
                int col = ct * 16 + lr;
                float b0 = (col < 41) ? bias[col] : 0.0f;
                float b1v = (col < 41) ? bias[41 + col] : 0.0f;
                float v0 = fmaxf(acc[0][rt][ct][i] + b0, 0.0f);
                float v1 = fmaxf(acc[1][rt][ct][i] + b1v, 0.0f);
                m[ct] = 0.5f * (v0 + v1);
                if (col < 41) mx = fmaxf(mx, m[ct]);
            }
#pragma unroll
            for (int msk = 1; msk < 16; msk <<= 1) mx = fmaxf(mx, __shfl_xor(mx, msk));
            float s = 0.0f;
#pragma unroll
            for (int ct = 0; ct < CT; ++ct) {
                int col = ct * 16 + lr;
                if (col < 41) s += __expf(m[ct] - mx);
            }
#pragma unroll
            for (int msk = 1; msk < 16; msk <<= 1) s += __shfl_xor(s, msk);
            float ls = __logf(s);
            if (n < N) {
#pragma unroll
                for (int ct = 0; ct < CT; ++ct) {
                    int col = ct * 16 + lr;
                    if (col < 41) out[(size_t)n * 41 + col] = m[ct] - mx - ls;
                }
            }
        }
    }
}

// ==================== CSR gather: 2 edges/wave-step, uint2 payload ====================
// lane = es*PAIRS + u; es in {0,1} handles edges beg+es, beg+es+2, ...
// lane loads row uints [2u, 2u+1]; halves combined via shfl at the end.
// pre (packed bf16, same layout) != null: out = bf16(relu(pre + agg)); else out = bf16(agg).
template<int PAIRS>
__global__ __launch_bounds__(256)
void gather2(const int* __restrict__ rowstart, const int* __restrict__ srcidx,
             const float* __restrict__ dinv, const uint_t* __restrict__ msg,
             const uint_t* __restrict__ pre, uint_t* __restrict__ outH, int N) {
    int gt = blockIdx.x * 256 + threadIdx.x;
    int n = gt >> 6, lane = gt & 63;
    if (n >= N) return;
    const int es = lane / PAIRS;
    const int u = lane % PAIRS;
    int beg = rowstart[n], end = rowstart[n + 1];
    float dn = dinv[n];
    float a0 = 0.f, a1 = 0.f, a2 = 0.f, a3 = 0.f;
    if (es < 2) {
        int e = beg + es;
        for (; e + 2 < end; e += 4) {
            int s0 = srcidx[e], s1 = srcidx[e + 2];
            float w0 = dinv[s0] * dn, w1 = dinv[s1] * dn;
            uint2 m0 = *(const uint2*)&msg[(size_t)s0 * (2 * PAIRS) + 2 * u];
            uint2 m1 = *(const uint2*)&msg[(size_t)s1 * (2 * PAIRS) + 2 * u];
            a0 = fmaf(bf2f((ushort_t)m0.x), w0, a0);
            a1 = fmaf(bf2f((ushort_t)(m0.x >> 16)), w0, a1);
            a2 = fmaf(bf2f((ushort_t)m0.y), w0, a2);
            a3 = fmaf(bf2f((ushort_t)(m0.y >> 16)), w0, a3);
            a0 = fmaf(bf2f((ushort_t)m1.x), w1, a0);
            a1 = fmaf(bf2f((ushort_t)(m1.x >> 16)), w1, a1);
            a2 = fmaf(bf2f((ushort_t)m1.y), w1, a2);
            a3 = fmaf(bf2f((ushort_t)(m1.y >> 16)), w1, a3);
        }
        if (e < end) {
            int s0 = srcidx[e];
            float w0 = dinv[s0] * dn;
            uint2 m0 = *(const uint2*)&msg[(size_t)s0 * (2 * PAIRS) + 2 * u];
            a0 = fmaf(bf2f((ushort_t)m0.x), w0, a0);
            a1 = fmaf(bf2f((ushort_t)(m0.x >> 16)), w0, a1);
            a2 = fmaf(bf2f((ushort_t)m0.y), w0, a2);
            a3 = fmaf(bf2f((ushort_t)(m0.y >> 16)), w0, a3);
        }
    }
    float b0 = __shfl(a0, u + PAIRS);
    float b1 = __shfl(a1, u + PAIRS);
    float b2 = __shfl(a2, u + PAIRS);
    float b3 = __shfl(a3, u + PAIRS);
    if (lane < PAIRS) {
        a0 += b0; a1 += b1; a2 += b2; a3 += b3;
        size_t o = (size_t)n * (2 * PAIRS) + 2 * u;
        if (pre) {
            uint2 p = *(const uint2*)&pre[o];
            a0 = fmaxf(a0 + bf2f((ushort_t)p.x), 0.f);
            a1 = fmaxf(a1 + bf2f((ushort_t)(p.x >> 16)), 0.f);
            a2 = fmaxf(a2 + bf2f((ushort_t)p.y), 0.f);
            a3 = fmaxf(a3 + bf2f((ushort_t)(p.y >> 16)), 0.f);
        }
        *(uint2*)&outH[o] = make_uint2(pack2(a0, a1), pack2(a2, a3));
    }
}

extern "C" void kernel_launch(void* const* d_in, const int* in_sizes, int n_in,
                              void* d_out, int out_size, void* d_ws, size_t ws_size,
                              hipStream_t stream) {
    const float* x       = (const float*)d_in[0];
    const int*   ei      = (const int*)  d_in[1];
    const float* w1_init = (const float*)d_in[2];
    const float* w1      = (const float*)d_in[3];
    const float* w1_root = (const float*)d_in[4];
    const float* b1      = (const float*)d_in[5];
    const float* w2_init = (const float*)d_in[6];
    const float* w2      = (const float*)d_in[7];
    const float* w2_root = (const float*)d_in[8];
    const float* b2      = (const float*)d_in[9];

    const int Fin1 = 128;
    int N = in_sizes[0] / Fin1;          // 100000
    int E = in_sizes[1] / 2;             // 1600000
    const int* row = ei;
    const int* col = ei + E;

    char* ws = (char*)d_ws;
    size_t off = 0;
    auto carve = [&](size_t bytes) -> void* {
        void* p = ws + off;
        off += (bytes + 255) & ~(size_t)255;
        return p;
    };
    int nblkN = (N + TPB - 1) / TPB;   // 391 (<=512 for one-block scan)
    int*      cnt      = (int*)     carve((size_t)N * 4);
    int*      incl     = (int*)     carve((size_t)N * 4);
    int*      rowstart = (int*)     carve((size_t)(N + 1) * 4);
    int*      bsum     = (int*)     carve((size_t)nblkN * 4);
    float*    dinv     = (float*)   carve((size_t)N * 4);
    int*      pos      = (int*)     carve((size_t)E * 4);
    int*      srcidx   = (int*)     carve((size_t)E * 4);
    short*    swz      = (short*)   carve((size_t)(SWZ_A + SWZ_B + SWZ_C + SWZ_D) * 2);
    ushort_t* xh       = (ushort_t*)carve((size_t)N * 128 * 2);      // bf16 x
    ushort_t* hh       = (ushort_t*)carve((size_t)N * 64 * 2);       // bf16 h
    ushort_t* b16A     = (ushort_t*)carve((size_t)N * 2 * 64 * 2);   // P / agg
    ushort_t* b16B     = (ushort_t*)carve((size_t)N * 2 * 64 * 2);   // out_t
    uint_t*   pre      = (uint_t*)  carve((size_t)N * 2 * 32 * 4);   // packed bf16 pre

    // ---- CSR + norm (atomic-free fill) ----
    hipMemsetAsync(cnt, 0, (size_t)N * 4, stream);
    rank_kernel <<<(E + TPB - 1) / TPB, TPB, 0, stream>>>(col, cnt, pos, E);
    scan_block  <<<nblkN, TPB, 0, stream>>>(cnt, incl, bsum, N);
    scan_bsums  <<<1, 512, 0, stream>>>(bsum, nblkN);
    finalize_csr<<<nblkN, TPB, 0, stream>>>(incl, bsum, cnt, rowstart, dinv, N);
    fill_csr    <<<(E + TPB - 1) / TPB, TPB, 0, stream>>>(row, col, rowstart, pos, srcidx, E);

    // ---- weight pre-swizzle + x -> bf16 ----
    int swztot = SWZ_A + SWZ_B + SWZ_C + SWZ_D;
    swz_all<<<(swztot + TPB - 1) / TPB, TPB, 0, stream>>>(w1_init, w1, w1_root,
                                                          w2_init, w2, w2_root, swz);
    int nx4 = N * 128 / 4;
    cvt4_kernel<<<(nx4 + TPB - 1) / TPB, TPB, 0, stream>>>((const float4*)x, (uint2*)xh, nx4);

    dim3 gg2((N + 127) / 128, 2);
    dim3 gg1((N + 127) / 128, 1);
    int ggb = (N * 64 + TPB - 1) / TPB;
    const short* swzA = swz;
    const short* swzB = swz + SWZ_A;
    const short* swzC = swz + SWZ_A + SWZ_B;
    const short* swzD = swz + SWZ_A + SWZ_B + SWZ_C;

    // ---- layer 1 (128 -> 64) ----
    gemm_t0<8, 4, 4><<<gg2, TPB, 0, stream>>>(xh, 128, swzA, b1, 64, N, pre, (uint_t*)b16A);
    gather2<32><<<ggb, TPB, 0, stream>>>(rowstart, srcidx, dinv, (const uint_t*)b16A,
                                         pre, (uint_t*)b16B, N);
    gather2<32><<<ggb, TPB, 0, stream>>>(rowstart, srcidx, dinv, (const uint_t*)b16B,
                                         nullptr, (uint_t*)b16A, N);
    gemm_t1_l1<<<gg1, TPB, 0, stream>>>(b16A, xh, swzB, b1 + 2 * 64, N, (uint_t*)hh);

    // ---- layer 2 (64 -> 41) ----
    gemm_t0<6, 3, 2><<<gg2, TPB, 0, stream>>>(hh, 64, swzC, b2, 41, N, pre, (uint_t*)b16A);
    gather2<24><<<ggb, TPB, 0, stream>>>(rowstart, srcidx, dinv, (const uint_t*)b16A,
                                         pre, (uint_t*)b16B, N);
    gather2<24><<<ggb, TPB, 0, stream>>>(rowstart, srcidx, dinv, (const uint_t*)b16B,
                                         nullptr, (uint_t*)b16A, N);
    gemm_t1_l2<<<gg1, TPB, 0, stream>>>(b16A, hh, swzD, b2 + 2 * 41, N, (float*)d_out);
}

// Round 8
// 604.165 us; speedup vs baseline: 1.1597x; 1.1597x over previous
//
#include <hip/hip_runtime.h>
#include <math.h>

#define TPB 256
typedef unsigned short ushort_t;
typedef unsigned int uint_t;
typedef __attribute__((ext_vector_type(8))) short bf16x8;
typedef __attribute__((ext_vector_type(4))) float f32x4;

__device__ __forceinline__ float bf2f(ushort_t h) {
    return __uint_as_float(((uint_t)h) << 16);
}
__device__ __forceinline__ ushort_t f2bf(float f) {
    uint_t u = __float_as_uint(f);
    u += 0x7fff + ((u >> 16) & 1);
    return (ushort_t)(u >> 16);
}
__device__ __forceinline__ uint_t pack2(float x, float y) {
    return (uint_t)f2bf(x) | ((uint_t)f2bf(y) << 16);
}

// ==================== CSR build + GCN norm ====================
__global__ void rank_kernel(const int* __restrict__ col, int* __restrict__ cnt,
                            int* __restrict__ pos, int E) {
    int e = blockIdx.x * blockDim.x + threadIdx.x;
    if (e < E) pos[e] = atomicAdd(&cnt[col[e]], 1);
}

__global__ void scan_block(const int* __restrict__ cnt, int* __restrict__ incl,
                           int* __restrict__ bsum, int N) {
    __shared__ int s[TPB];
    int i = blockIdx.x * TPB + threadIdx.x;
    s[threadIdx.x] = (i < N) ? cnt[i] : 0;
    __syncthreads();
    for (int d = 1; d < TPB; d <<= 1) {
        int t = (threadIdx.x >= d) ? s[threadIdx.x - d] : 0;
        __syncthreads();
        s[threadIdx.x] += t;
        __syncthreads();
    }
    if (i < N) incl[i] = s[threadIdx.x];
    if (threadIdx.x == TPB - 1) bsum[blockIdx.x] = s[TPB - 1];
}

__global__ void scan_bsums(int* __restrict__ bsum, int nb) {
    __shared__ int s[512];
    int t = threadIdx.x;
    int v = (t < nb) ? bsum[t] : 0;
    s[t] = v;
    __syncthreads();
    for (int d = 1; d < 512; d <<= 1) {
        int u = (t >= d) ? s[t - d] : 0;
        __syncthreads();
        s[t] += u;
        __syncthreads();
    }
    if (t < nb) bsum[t] = s[t] - v;
}

__global__ void finalize_csr(const int* __restrict__ incl, const int* __restrict__ bsum,
                             const int* __restrict__ cnt, int* __restrict__ rowstart,
                             float* __restrict__ dinv, int N) {
    int i = blockIdx.x * TPB + threadIdx.x;
    if (i < N) {
        rowstart[i + 1] = incl[i] + bsum[blockIdx.x];
        int d = cnt[i];
        dinv[i] = (d > 0) ? rsqrtf((float)d) : 0.0f;
    }
    if (i == 0) rowstart[0] = 0;
}

__global__ void fill_csr(const int* __restrict__ row, const int* __restrict__ col,
                         const int* __restrict__ rowstart, const int* __restrict__ pos,
                         int* __restrict__ srcidx, int E) {
    int e = blockIdx.x * blockDim.x + threadIdx.x;
    if (e < E) srcidx[rowstart[col[e]] + pos[e]] = row[e];
}

// ==================== conversion ====================
__global__ void cvt4_kernel(const float4* __restrict__ src, uint2* __restrict__ dst, int n4) {
    int i = blockIdx.x * blockDim.x + threadIdx.x;
    if (i < n4) {
        float4 v = src[i];
        dst[i] = make_uint2(pack2(v.x, v.y), pack2(v.z, v.w));
    }
}

// ==================== weight pre-swizzle (bf16 B-fragment order) ====================
#define SWZ_A 32768
#define SWZ_B 24576
#define SWZ_C 12288
#define SWZ_D 12288
__global__ void swz_all(const float* __restrict__ w1_init, const float* __restrict__ w1,
                        const float* __restrict__ w1_root, const float* __restrict__ w2_init,
                        const float* __restrict__ w2, const float* __restrict__ w2_root,
                        short* __restrict__ dst) {
    int idx = blockIdx.x * blockDim.x + threadIdx.x;
    int region, base, CH, CT;
    if (idx < SWZ_A)                          { region = 0; base = 0; CH = 4; CT = 8; }
    else if (idx < SWZ_A + SWZ_B)             { region = 1; base = SWZ_A; CH = 6; CT = 4; }
    else if (idx < SWZ_A + SWZ_B + SWZ_C)     { region = 2; base = SWZ_A + SWZ_B; CH = 2; CT = 6; }
    else if (idx < SWZ_A + SWZ_B + SWZ_C + SWZ_D)
                                              { region = 3; base = SWZ_A + SWZ_B + SWZ_C; CH = 4; CT = 3; }
    else return;
    int r = idx - base;
    int j = r & 7, ln = (r >> 3) & 63;
    int rest = r >> 9;
    int ct = rest % CT, c = (rest / CT) % CH, k = rest / (CT * CH);
    int col = ct * 16 + (ln & 15);
    int kl = (ln >> 4) * 8 + j;
    float v = 0.0f;
    if (region == 0) {              // L1-t0: x(128) -> [init(64) | root_t0(64)]
        int kk = c * 32 + kl;
        if (col < 64)       v = w1_init[((size_t)k * 128 + kk) * 64 + col];
        else                v = w1_root[((size_t)k * 128 + kk) * 64 + (col - 64)];
    } else if (region == 1) {       // L1-t1: c<2: agg(64)@w1 ; c>=2: x(128)@root_t1
        if (c < 2) { int kk = c * 32 + kl;        v = w1[((size_t)k * 64 + kk) * 64 + col]; }
        else       { int kk = (c - 2) * 32 + kl;  v = w1_root[((size_t)(2 + k) * 128 + kk) * 64 + col]; }
    } else if (region == 2) {       // L2-t0: h(64) -> [init(41,pad48) | root_t0(41,pad48)]
        int kk = c * 32 + kl;
        if (col < 48) { if (col < 41)            v = w2_init[((size_t)k * 64 + kk) * 41 + col]; }
        else          { int c2 = col - 48; if (c2 < 41) v = w2_root[((size_t)k * 64 + kk) * 41 + c2]; }
    } else {                        // L2-t1: c<2: agg(48,rows41)@w2 ; c>=2: h(64)@root_t1
        if (c < 2) { int kk = c * 32 + kl;       if (kk < 41 && col < 41) v = w2[((size_t)k * 41 + kk) * 41 + col]; }
        else       { int kk = (c - 2) * 32 + kl; if (col < 41)            v = w2_root[((size_t)(2 + k) * 64 + kk) * 41 + col]; }
    }
    dst[(size_t)base + r] = (short)f2bf(v);
}

// ==================== t0 GEMM (per-k): s2 @ [Wa | Wb] -> outH bf16 + pre bf16 ====================
template<int CT, int CTA, int CH>
__global__ __launch_bounds__(256)
void gemm_t0(const ushort_t* __restrict__ s2, int s2s, const short* __restrict__ fragbuf,
             const float* __restrict__ biasB, int FB, int N,
             uint_t* __restrict__ pre, uint_t* __restrict__ outH) {
    constexpr int PP = (CT - CTA) * 8;
    constexpr int PA = CTA * 8;
    const int k = blockIdx.y;
    const int n0 = blockIdx.x * 128;
    const int t = threadIdx.x;
    const int w = t >> 6, lane = t & 63, quad = lane >> 4, lr = lane & 15;
    const short* fb = fragbuf + (size_t)k * CH * CT * 512;

    int r0 = n0 + w * 32 + lr;
    int m0 = r0 < N ? r0 : N - 1;
    int m1 = (r0 + 16) < N ? (r0 + 16) : N - 1;

    f32x4 acc[2][CT];
#pragma unroll
    for (int rt = 0; rt < 2; ++rt)
#pragma unroll
        for (int ct = 0; ct < CT; ++ct) acc[rt][ct] = (f32x4){0.f, 0.f, 0.f, 0.f};

#pragma unroll
    for (int c = 0; c < CH; ++c) {
        int off = c * 32 + quad * 8;
        bf16x8 a0 = *(const bf16x8*)&s2[(size_t)m0 * s2s + off];
        bf16x8 a1 = *(const bf16x8*)&s2[(size_t)m1 * s2s + off];
#pragma unroll
        for (int ct = 0; ct < CT; ++ct) {
            bf16x8 b = *(const bf16x8*)&fb[((size_t)c * CT + ct) * 512 + lane * 8];
            acc[0][ct] = __builtin_amdgcn_mfma_f32_16x16x32_bf16(a0, b, acc[0][ct], 0, 0, 0);
            acc[1][ct] = __builtin_amdgcn_mfma_f32_16x16x32_bf16(a1, b, acc[1][ct], 0, 0, 0);
        }
    }

#pragma unroll
    for (int rt = 0; rt < 2; ++rt) {
#pragma unroll
        for (int i = 0; i < 4; ++i) {
            int n = n0 + w * 32 + rt * 16 + quad * 4 + i;
            if (n >= N) continue;
#pragma unroll
            for (int ct = 0; ct < CT; ++ct) {
                int col = ct * 16 + lr;
                float v = acc[rt][ct][i];
                if (ct < CTA) {
                    float vn = __shfl_xor(v, 1);
                    if (!(lr & 1))
                        outH[((size_t)n * 2 + k) * PA + (col >> 1)] = pack2(v, vn);
                } else {
                    int c2 = col - CTA * 16;
                    if (c2 < FB) v += biasB[(size_t)k * FB + c2];
                    float vn = __shfl_xor(v, 1);
                    if (!(lr & 1))
                        pre[((size_t)n * 2 + k) * PP + (c2 >> 1)] = pack2(v, vn);
                }
            }
        }
    }
}

// ==================== t1 GEMM layer1: relu+mean -> hh bf16 ====================
__global__ __launch_bounds__(256)
void gemm_t1_l1(const ushort_t* __restrict__ s1, const ushort_t* __restrict__ xh,
                const short* __restrict__ fragbuf, const float* __restrict__ bias,
                int N, uint_t* __restrict__ hhU) {
    constexpr int CT = 4, CH = 6;
    const int n0 = blockIdx.x * 128;
    const int t = threadIdx.x;
    const int w = t >> 6, lane = t & 63, quad = lane >> 4, lr = lane & 15;

    int r0 = n0 + w * 32 + lr;
    int m0 = r0 < N ? r0 : N - 1;
    int m1 = (r0 + 16) < N ? (r0 + 16) : N - 1;

    f32x4 acc[2][2][CT];
#pragma unroll
    for (int k = 0; k < 2; ++k)
#pragma unroll
        for (int rt = 0; rt < 2; ++rt)
#pragma unroll
            for (int ct = 0; ct < CT; ++ct) acc[k][rt][ct] = (f32x4){0.f, 0.f, 0.f, 0.f};

#pragma unroll
    for (int c = 0; c < CH; ++c) {
        bf16x8 a0[2], a1[2];
        if (c < 2) {
            int off = c * 32 + quad * 8;
#pragma unroll
            for (int k = 0; k < 2; ++k) {
                a0[k] = *(const bf16x8*)&s1[((size_t)m0 * 2 + k) * 64 + off];
                a1[k] = *(const bf16x8*)&s1[((size_t)m1 * 2 + k) * 64 + off];
            }
        } else {
            int off = (c - 2) * 32 + quad * 8;
            a0[0] = a0[1] = *(const bf16x8*)&xh[(size_t)m0 * 128 + off];
            a1[0] = a1[1] = *(const bf16x8*)&xh[(size_t)m1 * 128 + off];
        }
#pragma unroll
        for (int k = 0; k < 2; ++k) {
            const short* fb = fragbuf + (size_t)k * CH * CT * 512;
#pragma unroll
            for (int ct = 0; ct < CT; ++ct) {
                bf16x8 b = *(const bf16x8*)&fb[((size_t)c * CT + ct) * 512 + lane * 8];
                acc[k][0][ct] = __builtin_amdgcn_mfma_f32_16x16x32_bf16(a0[k], b, acc[k][0][ct], 0, 0, 0);
                acc[k][1][ct] = __builtin_amdgcn_mfma_f32_16x16x32_bf16(a1[k], b, acc[k][1][ct], 0, 0, 0);
            }
        }
    }

#pragma unroll
    for (int rt = 0; rt < 2; ++rt) {
#pragma unroll
        for (int i = 0; i < 4; ++i) {
            int n = n0 + w * 32 + rt * 16 + quad * 4 + i;
            if (n >= N) continue;
#pragma unroll
            for (int ct = 0; ct < CT; ++ct) {
                int col = ct * 16 + lr;
                float v0 = fmaxf(acc[0][rt][ct][i] + bias[col], 0.0f);
                float v1 = fmaxf(acc[1][rt][ct][i] + bias[64 + col], 0.0f);
                float m = 0.5f * (v0 + v1);
                float mn = __shfl_xor(m, 1);
                if (!(lr & 1)) hhU[(size_t)n * 32 + (col >> 1)] = pack2(m, mn);
            }
        }
    }
}

// ===== t1 GEMM layer2: relu+mean+log_softmax -> d_out f32 =====
__global__ __launch_bounds__(256)
void gemm_t1_l2(const ushort_t* __restrict__ s1, const ushort_t* __restrict__ hh,
                const short* __restrict__ fragbuf, const float* __restrict__ bias,
                int N, float* __restrict__ out) {
    constexpr int CT = 3, CH = 4;
    const int n0 = blockIdx.x * 128;
    const int t = threadIdx.x;
    const int w = t >> 6, lane = t & 63, quad = lane >> 4, lr = lane & 15;

    int r0 = n0 + w * 32 + lr;
    int m0 = r0 < N ? r0 : N - 1;
    int m1 = (r0 + 16) < N ? (r0 + 16) : N - 1;

    f32x4 acc[2][2][CT];
#pragma unroll
    for (int k = 0; k < 2; ++k)
#pragma unroll
        for (int rt = 0; rt < 2; ++rt)
#pragma unroll
            for (int ct = 0; ct < CT; ++ct) acc[k][rt][ct] = (f32x4){0.f, 0.f, 0.f, 0.f};

#pragma unroll
    for (int c = 0; c < CH; ++c) {
        bf16x8 a0[2], a1[2];
        if (c < 2) {
            int off = c * 32 + quad * 8;
#pragma unroll
            for (int k = 0; k < 2; ++k) {
                a0[k] = *(const bf16x8*)&s1[((size_t)m0 * 2 + k) * 48 + off];
                a1[k] = *(const bf16x8*)&s1[((size_t)m1 * 2 + k) * 48 + off];
            }
        } else {
            int off = (c - 2) * 32 + quad * 8;
            a0[0] = a0[1] = *(const bf16x8*)&hh[(size_t)m0 * 64 + off];
            a1[0] = a1[1] = *(const bf16x8*)&hh[(size_t)m1 * 64 + off];
        }
#pragma unroll
        for (int k = 0; k < 2; ++k) {
            const short* fb = fragbuf + (size_t)k * CH * CT * 512;
#pragma unroll
            for (int ct = 0; ct < CT; ++ct) {
                bf16x8 b = *(const bf16x8*)&fb[((size_t)c * CT + ct) * 512 + lane * 8];
                acc[k][0][ct] = __builtin_amdgcn_mfma_f32_16x16x32_bf16(a0[k], b, acc[k][0][ct], 0, 0, 0);
                acc[k][1][ct] = __builtin_amdgcn_mfma_f32_16x16x32_bf16(a1[k], b, acc[k][1][ct], 0, 0, 0);
            }
        }
    }

#pragma unroll
    for (int rt = 0; rt < 2; ++rt) {
#pragma unroll
        for (int i = 0; i < 4; ++i) {
            int n = n0 + w * 32 + rt * 16 + quad * 4 + i;
            float m[CT];
            float mx = -1e30f;
#pragma unroll
            for (int ct = 0; ct < CT; ++ct) {
                int col = ct * 16 + lr;
                float b0 = (col < 41) ? bias[col] : 0.0f;
                float b1v = (col < 41) ? bias[41 + col] : 0.0f;
                float v0 = fmaxf(acc[0][rt][ct][i] + b0, 0.0f);
                float v1 = fmaxf(acc[1][rt][ct][i] + b1v, 0.0f);
                m[ct] = 0.5f * (v0 + v1);
                if (col < 41) mx = fmaxf(mx, m[ct]);
            }
#pragma unroll
            for (int msk = 1; msk < 16; msk <<= 1) mx = fmaxf(mx, __shfl_xor(mx, msk));
            float s = 0.0f;
#pragma unroll
            for (int ct = 0; ct < CT; ++ct) {
                int col = ct * 16 + lr;
                if (col < 41) s += __expf(m[ct] - mx);
            }
#pragma unroll
            for (int msk = 1; msk < 16; msk <<= 1) s += __shfl_xor(s, msk);
            float ls = __logf(s);
            if (n < N) {
#pragma unroll
                for (int ct = 0; ct < CT; ++ct) {
                    int col = ct * 16 + lr;
                    if (col < 41) out[(size_t)n * 41 + col] = m[ct] - mx - ls;
                }
            }
        }
    }
}

// ==================== CSR gather: 1 uint/lane, 8 edges in flight ====================
// lane -> (k, pair); row payload [s][2][PAIRS] uints; pre packed bf16 same layout.
template<int PAIRS>
__global__ __launch_bounds__(256)
void gather(const int* __restrict__ rowstart, const int* __restrict__ srcidx,
            const float* __restrict__ dinv, const uint_t* __restrict__ msg,
            const uint_t* __restrict__ pre, uint_t* __restrict__ outH, int N) {
    int gt = blockIdx.x * 256 + threadIdx.x;
    int n = gt >> 6, lane = gt & 63;
    if (n >= N) return;
    int k, pair;
    if (PAIRS == 32) { k = lane >> 5; pair = lane & 31; }
    else { k = lane / PAIRS; pair = lane - k * PAIRS; }
    if (k >= 2) return;
    int beg = rowstart[n], end = rowstart[n + 1];
    float dn = dinv[n];
    float ax = 0.0f, ay = 0.0f;
    int e = beg;
    for (; e + 7 < end; e += 8) {
        int s[8];
        float w[8];
        uint_t m[8];
#pragma unroll
        for (int j = 0; j < 8; ++j) s[j] = srcidx[e + j];
#pragma unroll
        for (int j = 0; j < 8; ++j) w[j] = dinv[s[j]];
#pragma unroll
        for (int j = 0; j < 8; ++j) m[j] = msg[((size_t)s[j] * 2 + k) * PAIRS + pair];
#pragma unroll
        for (int j = 0; j < 8; ++j) {
            float ww = w[j] * dn;
            ax = fmaf(bf2f((ushort_t)m[j]), ww, ax);
            ay = fmaf(bf2f((ushort_t)(m[j] >> 16)), ww, ay);
        }
    }
    if (e + 3 < end) {
        int s[4];
        float w[4];
        uint_t m[4];
#pragma unroll
        for (int j = 0; j < 4; ++j) s[j] = srcidx[e + j];
#pragma unroll
        for (int j = 0; j < 4; ++j) w[j] = dinv[s[j]];
#pragma unroll
        for (int j = 0; j < 4; ++j) m[j] = msg[((size_t)s[j] * 2 + k) * PAIRS + pair];
#pragma unroll
        for (int j = 0; j < 4; ++j) {
            float ww = w[j] * dn;
            ax = fmaf(bf2f((ushort_t)m[j]), ww, ax);
            ay = fmaf(bf2f((ushort_t)(m[j] >> 16)), ww, ay);
        }
        e += 4;
    }
    for (; e < end; ++e) {
        int s0 = srcidx[e];
        float ww = dinv[s0] * dn;
        uint_t m0 = msg[((size_t)s0 * 2 + k) * PAIRS + pair];
        ax = fmaf(bf2f((ushort_t)m0), ww, ax);
        ay = fmaf(bf2f((ushort_t)(m0 >> 16)), ww, ay);
    }
    size_t o = ((size_t)n * 2 + k) * PAIRS + pair;
    if (pre) {
        uint_t p = pre[o];
        ax = fmaxf(ax + bf2f((ushort_t)p), 0.0f);
        ay = fmaxf(ay + bf2f((ushort_t)(p >> 16)), 0.0f);
    }
    outH[o] = pack2(ax, ay);
}

extern "C" void kernel_launch(void* const* d_in, const int* in_sizes, int n_in,
                              void* d_out, int out_size, void* d_ws, size_t ws_size,
                              hipStream_t stream) {
    const float* x       = (const float*)d_in[0];
    const int*   ei      = (const int*)  d_in[1];
    const float* w1_init = (const float*)d_in[2];
    const float* w1      = (const float*)d_in[3];
    const float* w1_root = (const float*)d_in[4];
    const float* b1      = (const float*)d_in[5];
    const float* w2_init = (const float*)d_in[6];
    const float* w2      = (const float*)d_in[7];
    const float* w2_root = (const float*)d_in[8];
    const float* b2      = (const float*)d_in[9];

    const int Fin1 = 128;
    int N = in_sizes[0] / Fin1;          // 100000
    int E = in_sizes[1] / 2;             // 1600000
    const int* row = ei;
    const int* col = ei + E;

    char* ws = (char*)d_ws;
    size_t off = 0;
    auto carve = [&](size_t bytes) -> void* {
        void* p = ws + off;
        off += (bytes + 255) & ~(size_t)255;
        return p;
    };
    int nblkN = (N + TPB - 1) / TPB;   // 391 (<=512 for one-block scan)
    int*      cnt      = (int*)     carve((size_t)N * 4);
    int*      incl     = (int*)     carve((size_t)N * 4);
    int*      rowstart = (int*)     carve((size_t)(N + 1) * 4);
    int*      bsum     = (int*)     carve((size_t)nblkN * 4);
    float*    dinv     = (float*)   carve((size_t)N * 4);
    int*      pos      = (int*)     carve((size_t)E * 4);
    int*      srcidx   = (int*)     carve((size_t)E * 4);
    short*    swz      = (short*)   carve((size_t)(SWZ_A + SWZ_B + SWZ_C + SWZ_D) * 2);
    ushort_t* xh       = (ushort_t*)carve((size_t)N * 128 * 2);      // bf16 x
    ushort_t* hh       = (ushort_t*)carve((size_t)N * 64 * 2);       // bf16 h
    ushort_t* b16A     = (ushort_t*)carve((size_t)N * 2 * 64 * 2);   // P / agg
    ushort_t* b16B     = (ushort_t*)carve((size_t)N * 2 * 64 * 2);   // out_t
    uint_t*   pre      = (uint_t*)  carve((size_t)N * 2 * 32 * 4);   // packed bf16 pre

    // ---- CSR + norm (atomic-free fill) ----
    hipMemsetAsync(cnt, 0, (size_t)N * 4, stream);
    rank_kernel <<<(E + TPB - 1) / TPB, TPB, 0, stream>>>(col, cnt, pos, E);
    scan_block  <<<nblkN, TPB, 0, stream>>>(cnt, incl, bsum, N);
    scan_bsums  <<<1, 512, 0, stream>>>(bsum, nblkN);
    finalize_csr<<<nblkN, TPB, 0, stream>>>(incl, bsum, cnt, rowstart, dinv, N);
    fill_csr    <<<(E + TPB - 1) / TPB, TPB, 0, stream>>>(row, col, rowstart, pos, srcidx, E);

    // ---- weight pre-swizzle + x -> bf16 ----
    int swztot = SWZ_A + SWZ_B + SWZ_C + SWZ_D;
    swz_all<<<(swztot + TPB - 1) / TPB, TPB, 0, stream>>>(w1_init, w1, w1_root,
                                                          w2_init, w2, w2_root, swz);
    int nx4 = N * 128 / 4;
    cvt4_kernel<<<(nx4 + TPB - 1) / TPB, TPB, 0, stream>>>((const float4*)x, (uint2*)xh, nx4);

    dim3 gg2((N + 127) / 128, 2);
    dim3 gg1((N + 127) / 128, 1);
    int ggb = (N * 64 + TPB - 1) / TPB;
    const short* swzA = swz;
    const short* swzB = swz + SWZ_A;
    const short* swzC = swz + SWZ_A + SWZ_B;
    const short* swzD = swz + SWZ_A + SWZ_B + SWZ_C;

    // ---- layer 1 (128 -> 64) ----
    gemm_t0<8, 4, 4><<<gg2, TPB, 0, stream>>>(xh, 128, swzA, b1, 64, N, pre, (uint_t*)b16A);
    gather<32><<<ggb, TPB, 0, stream>>>(rowstart, srcidx, dinv, (const uint_t*)b16A,
                                        pre, (uint_t*)b16B, N);
    gather<32><<<ggb, TPB, 0, stream>>>(rowstart, srcidx, dinv, (const uint_t*)b16B,
                                        nullptr, (uint_t*)b16A, N);
    gemm_t1_l1<<<gg1, TPB, 0, stream>>>(b16A, xh, swzB, b1 + 2 * 64, N, (uint_t*)hh);

    // ---- layer 2 (64 -> 41) ----
    gemm_t0<6, 3, 2><<<gg2, TPB, 0, stream>>>(hh, 64, swzC, b2, 41, N, pre, (uint_t*)b16A);
    gather<24><<<ggb, TPB, 0, stream>>>(rowstart, srcidx, dinv, (const uint_t*)b16A,
                                        pre, (uint_t*)b16B, N);
    gather<24><<<ggb, TPB, 0, stream>>>(rowstart, srcidx, dinv, (const uint_t*)b16B,
                                        nullptr, (uint_t*)b16A, N);
    gemm_t1_l2<<<gg1, TPB, 0, stream>>>(b16A, hh, swzD, b2 + 2 * 41, N, (float*)d_out);
}